// Round 3
// baseline (86.741 us; speedup 1.0000x reference)
//
#include <hip/hip_runtime.h>

#define POOL 7
#define CCH 256
#define GCH 8             // channels per block
#define HH 100
#define WW 100
#define HW (HH * WW)
#define MAXSPAN 28        // worst-case ROI sub-tile span is <=26; +2 margin
#define NTAP 14           // POOL * NSAMP samples per axis
#define RECI 128          // ints per ROI record in scratch

static constexpr float SCALE = 0.125f;

__device__ int g_rec[1024 * RECI];   // fallback if d_ws too small

__device__ __forceinline__ void tap_calc(float s0, float step, int k, int L,
                                         int& lo, int& hi, float& w1, float& w2)
{
    const int   p  = k >> 1, si = k & 1;
    const float g  = (float)p + ((float)si + 0.5f) * 0.5f;
    const float c  = s0 + g * step;
    const float Lf = (float)L;
    const bool  valid = (c > -1.0f) && (c < Lf);
    float cl = fminf(fmaxf(c, 0.0f), Lf - 1.0f);
    lo = (int)floorf(cl);
    if (lo > L - 1) lo = L - 1;
    hi = lo + 1;
    if (hi > L - 1) hi = L - 1;
    const float fr = cl - (float)lo;
    w1 = valid ? 1.0f - fr : 0.0f;
    w2 = valid ? fr : 0.0f;
}

// One wave per ROI: build {n, xmin, ymin, TW, TH} + 28 taps (tile-relative).
__global__ __launch_bounds__(64) void roi_pre(const float* __restrict__ rois,
                                              int* __restrict__ rec, int R)
{
    const int r = blockIdx.x;
    if (r >= R) return;
    int* rr = (rec ? rec : g_rec) + r * RECI;
    const int t = threadIdx.x;

    const float r0  = rois[r * 5 + 0];
    const float sx0 = rois[r * 5 + 1] * SCALE - 0.5f;
    const float sy0 = rois[r * 5 + 2] * SCALE - 0.5f;
    const float bw  = (rois[r * 5 + 3] * SCALE - 0.5f - sx0) * (1.0f / POOL);
    const float bh  = (rois[r * 5 + 4] * SCALE - 0.5f - sy0) * (1.0f / POOL);

    if (t < 2 * NTAP) {
        const int axis = t / NTAP;       // 0=x, 1=y
        const int k    = t % NTAP;
        int lo, hi, lo0, d0; float w1, w2, d1, d2;
        if (axis == 0) {
            tap_calc(sx0, bw, k, WW, lo, hi, w1, w2);
            tap_calc(sx0, bw, 0, WW, lo0, d0, d1, d2);
        } else {
            tap_calc(sy0, bh, k, HH, lo, hi, w1, w2);
            tap_calc(sy0, bh, 0, HH, lo0, d0, d1, d2);
        }
        int* tp = rr + 8 + axis * 4 * NTAP + k * 4;
        tp[0] = min(lo - lo0, MAXSPAN - 1);
        tp[1] = min(hi - lo0, MAXSPAN - 1);
        tp[2] = __float_as_int(w1);
        tp[3] = __float_as_int(w2);
    } else if (t == 2 * NTAP) {
        // bin_w/bin_h > 0 -> taps monotonic -> bounds from taps 0 and 13
        int xl0, xh0, xl13, xh13, yl0, yh0, yl13, yh13; float a, b;
        tap_calc(sx0, bw, 0,        WW, xl0,  xh0,  a, b);
        tap_calc(sx0, bw, NTAP - 1, WW, xl13, xh13, a, b);
        tap_calc(sy0, bh, 0,        HH, yl0,  yh0,  a, b);
        tap_calc(sy0, bh, NTAP - 1, HH, yl13, yh13, a, b);
        int TW = xh13 - xl0 + 1; if (TW > MAXSPAN) TW = MAXSPAN;
        int TH = yh13 - yl0 + 1; if (TH > MAXSPAN) TH = MAXSPAN;
        rr[0] = (int)r0; rr[1] = xl0; rr[2] = yl0; rr[3] = TW; rr[4] = TH;
    }
}

// One block per (roi, 8-channel group); 6 blocks/CU (LDS), VGPR<=64 forced.
__global__ __launch_bounds__(256, 8) void roi_main(
    const float* __restrict__ x, const int* __restrict__ rec_in,
    float* __restrict__ out)
{
    __shared__ float tile[GCH * MAXSPAN * MAXSPAN];   // 25088 B
    __shared__ int   s_tap[2 * NTAP * 4];             // 448 B

    const int bid = blockIdx.x;
    const int r   = bid >> 5;                         // CCH/GCH = 32 groups
    const int c0  = (bid & 31) * GCH;
    const int t   = threadIdx.x;

    const int* rr = (rec_in ? rec_in : g_rec) + r * RECI;
    const int n = rr[0], xmin = rr[1], ymin = rr[2], TW = rr[3], TH = rr[4];

    if (t < 2 * NTAP * 4) s_tap[t] = rr[8 + t];

    const int chstride = TH * TW;

    // ---- stage: W-coalesced rows, all loads issued up front ----
    {
        const float* xb = x + ((size_t)n * CCH + c0) * HW
                            + (size_t)ymin * WW + xmin;
        const int tx = t & 31;
        const int ty = t >> 5;
        if (tx < TW) {
            #pragma unroll
            for (int ch = 0; ch < GCH; ++ch) {
                #pragma unroll
                for (int j = 0; j < (MAXSPAN + 7) / 8; ++j) {
                    const int yy = ty + j * 8;
                    if (yy < TH)
                        tile[ch * chstride + yy * TW + tx] =
                            xb[(size_t)ch * HW + yy * WW + tx];
                }
            }
        }
    }
    __syncthreads();

    // ---- compute: thread = (channel, 2 bins), all reads from LDS ----
    const int    ch = t >> 5;            // 0..7
    const int    bl = t & 31;
    const float* tc = tile + ch * chstride;
    float*       op = out + ((size_t)r * CCH + c0 + ch) * (POOL * POOL);

    #pragma unroll
    for (int i = 0; i < 2; ++i) {
        const int b = bl + i * 32;
        if (b < POOL * POOL) {
            const int py = b / POOL;
            const int px = b - py * POOL;
            float acc = 0.0f;
            #pragma unroll
            for (int sy = 0; sy < 2; ++sy) {
                const int  ky  = py * 2 + sy;
                const int* yt  = s_tap + NTAP * 4 + ky * 4;
                const int  yl  = yt[0], yh = yt[1];
                const float wy1 = __int_as_float(yt[2]);
                const float wy2 = __int_as_float(yt[3]);
                #pragma unroll
                for (int sx = 0; sx < 2; ++sx) {
                    const int  kx  = px * 2 + sx;
                    const int* xt  = s_tap + kx * 4;
                    const int  xl  = xt[0], xh = xt[1];
                    const float wx1 = __int_as_float(xt[2]);
                    const float wx2 = __int_as_float(xt[3]);
                    acc += wy1 * (wx1 * tc[yl * TW + xl] + wx2 * tc[yl * TW + xh])
                         + wy2 * (wx1 * tc[yh * TW + xl] + wx2 * tc[yh * TW + xh]);
                }
            }
            op[b] = acc * 0.25f;
        }
    }
}

extern "C" void kernel_launch(void* const* d_in, const int* in_sizes, int n_in,
                              void* d_out, int out_size, void* d_ws, size_t ws_size,
                              hipStream_t stream) {
    const float* x    = (const float*)d_in[0];
    const float* rois = (const float*)d_in[1];
    float*       out  = (float*)d_out;

    const int R = in_sizes[1] / 5;
    int* rec = (ws_size >= (size_t)R * RECI * sizeof(int)) ? (int*)d_ws : nullptr;

    roi_pre<<<R, 64, 0, stream>>>(rois, rec, R);
    roi_main<<<R * (CCH / GCH), 256, 0, stream>>>(x, rec, out);
}

// Round 4
// 49.131 us; speedup vs baseline: 1.7655x; 1.7655x over previous
//
#include <hip/hip_runtime.h>

#define POOL 7
#define CCH 256
#define GCH 8             // channels per block
#define HH 100
#define WW 100
#define HW (HH * WW)
#define MAXTH 28          // worst-case row span (<=27)
#define NTAP 14           // POOL * NSAMP samples per axis
#define RECI 128          // ints per ROI record
#define NT 512            // threads per main block

static constexpr float SCALE = 0.125f;

__device__ int g_rec[1024 * RECI];   // fallback if d_ws too small

__device__ __forceinline__ void tap_calc(float s0, float step, int k, int L,
                                         int& lo, int& hi, float& w1, float& w2)
{
    const int   p  = k >> 1, si = k & 1;
    const float g  = (float)p + ((float)si + 0.5f) * 0.5f;
    const float c  = s0 + g * step;
    const float Lf = (float)L;
    const bool  valid = (c > -1.0f) && (c < Lf);
    float cl = fminf(fmaxf(c, 0.0f), Lf - 1.0f);
    lo = (int)floorf(cl);
    if (lo > L - 1) lo = L - 1;
    hi = lo + 1;
    if (hi > L - 1) hi = L - 1;
    const float fr = cl - (float)lo;
    w1 = valid ? 1.0f - fr : 0.0f;
    w2 = valid ? fr : 0.0f;
}

// Per ROI: {n, xmin_al, ymin, TH} + 28 taps. x taps relative to xmin_al
// (4-aligned), y taps relative to ymin. Taps monotonic (bin_w, bin_h > 0).
__global__ __launch_bounds__(64) void roi_pre(const float* __restrict__ rois,
                                              int* __restrict__ rec, int R)
{
    const int r = blockIdx.x;
    if (r >= R) return;
    int* rr = (rec ? rec : g_rec) + r * RECI;
    const int t = threadIdx.x;

    const float sx0 = rois[r * 5 + 1] * SCALE - 0.5f;
    const float sy0 = rois[r * 5 + 2] * SCALE - 0.5f;
    const float bw  = (rois[r * 5 + 3] * SCALE - 0.5f - sx0) * (1.0f / POOL);
    const float bh  = (rois[r * 5 + 4] * SCALE - 0.5f - sy0) * (1.0f / POOL);

    if (t < 2 * NTAP) {
        const int   axis = (t >= NTAP) ? 1 : 0;
        const int   k    = axis ? t - NTAP : t;
        const float s0   = axis ? sy0 : sx0;
        const float st   = axis ? bh : bw;
        const int   L    = axis ? HH : WW;
        int lo, hi, lo0, u0; float w1, w2, ua, ub;
        tap_calc(s0, st, k, L, lo, hi, w1, w2);
        tap_calc(s0, st, 0, L, lo0, u0, ua, ub);
        const int base = axis ? lo0 : (lo0 & ~3);
        const int cap  = axis ? (MAXTH - 1) : 31;
        int* tp = rr + 8 + (axis ? 4 * NTAP : 0) + k * 4;
        tp[0] = min(max(lo - base, 0), cap);
        tp[1] = min(max(hi - base, 0), cap);
        tp[2] = __float_as_int(w1);
        tp[3] = __float_as_int(w2);
    } else if (t == 2 * NTAP) {
        int xl0, xh0, yl0, yh0, yl13, yh13; float a, b;
        tap_calc(sx0, bw, 0,        WW, xl0,  xh0,  a, b);
        tap_calc(sy0, bh, 0,        HH, yl0,  yh0,  a, b);
        tap_calc(sy0, bh, NTAP - 1, HH, yl13, yh13, a, b);
        int TH = yh13 - yl0 + 1; if (TH > MAXTH) TH = MAXTH;
        rr[0] = (int)rois[r * 5 + 0];
        rr[1] = xl0 & ~3;
        rr[2] = yl0;
        rr[3] = TH;
    }
}

// One block per (roi, 8-channel group), 512 threads, 4 blocks/CU.
// Staging: async global->LDS (fire-and-forget, one barrier), rows padded to
// 32 floats, XOR block-swizzled via pre-swizzled global source (T2/m173).
__global__ __launch_bounds__(NT, 8) void roi_main(
    const float* __restrict__ x, const int* __restrict__ rec_in,
    float* __restrict__ out)
{
    __shared__ float tile[GCH * MAXTH * 32];      // 28672 B
    __shared__ int   s_tap[2 * NTAP * 4];         // 448 B

    const int bid = blockIdx.x;
    const int r   = bid >> 5;                     // CCH/GCH = 32 groups/ROI
    const int c0  = (bid & 31) * GCH;
    const int t   = threadIdx.x;

    const int* rr = (rec_in ? rec_in : g_rec) + r * RECI;
    const int n = rr[0], xmin_al = rr[1], ymin = rr[2], TH = rr[3];

    if (t < 2 * NTAP * 4) s_tap[t] = rr[8 + t];

    // ---- async staging: thread t covers (row = t>>3, 16B block b = t&7) ----
    {
        const int row = t >> 3;
        const int b   = t & 7;
        if (row < TH) {
            const int rb = row & 7;
            int sc = xmin_al + ((b ^ rb) << 2);   // pre-swizzled source block
            if (sc > WW - 4) sc = WW - 4;         // provably-unused blocks only
            const float* gsrc = x + (size_t)(n * CCH + c0) * HW
                                  + (ymin + row) * WW + sc;
            float* ldst = tile + row * 32 + (b << 2);   // lane-linear: t*16B
            #pragma unroll
            for (int ch = 0; ch < GCH; ++ch) {
                __builtin_amdgcn_global_load_lds(
                    (const __attribute__((address_space(1))) void*)(gsrc + (size_t)ch * HW),
                    (__attribute__((address_space(3))) void*)(ldst + ch * (MAXTH * 32)),
                    16, 0, 0);
            }
        }
    }
    __syncthreads();

    // ---- compute: thread = (channel = t>>6, bin = t&63) ----
    const int ch  = t >> 6;
    const int bin = t & 63;
    if (bin < POOL * POOL) {
        const int py = bin / POOL;
        const int px = bin - py * POOL;
        const float* tc = tile + ch * (MAXTH * 32);
        float acc = 0.0f;
        #pragma unroll
        for (int sy = 0; sy < 2; ++sy) {
            const int* yt = s_tap + 4 * NTAP + (py * 2 + sy) * 4;
            const int   yl  = yt[0], yh = yt[1];
            const float wy1 = __int_as_float(yt[2]);
            const float wy2 = __int_as_float(yt[3]);
            const int rowl = yl << 5, rowh = yh << 5;
            const int swl  = (yl & 7) << 2, swh = (yh & 7) << 2;
            #pragma unroll
            for (int sx = 0; sx < 2; ++sx) {
                const int* xt = s_tap + (px * 2 + sx) * 4;
                const int   xl  = xt[0], xh = xt[1];
                const float wx1 = __int_as_float(xt[2]);
                const float wx2 = __int_as_float(xt[3]);
                acc += wy1 * (wx1 * tc[rowl + (xl ^ swl)] + wx2 * tc[rowl + (xh ^ swl)])
                     + wy2 * (wx1 * tc[rowh + (xl ^ swh)] + wx2 * tc[rowh + (xh ^ swh)]);
            }
        }
        out[(size_t)(r * CCH + c0 + ch) * (POOL * POOL) + bin] = acc * 0.25f;
    }
}

extern "C" void kernel_launch(void* const* d_in, const int* in_sizes, int n_in,
                              void* d_out, int out_size, void* d_ws, size_t ws_size,
                              hipStream_t stream) {
    const float* x    = (const float*)d_in[0];
    const float* rois = (const float*)d_in[1];
    float*       out  = (float*)d_out;

    const int R = in_sizes[1] / 5;
    int* rec = (ws_size >= (size_t)R * RECI * sizeof(int)) ? (int*)d_ws : nullptr;

    roi_pre<<<R, 64, 0, stream>>>(rois, rec, R);
    roi_main<<<R * (CCH / GCH), NT, 0, stream>>>(x, rec, out);
}

// Round 5
// 42.941 us; speedup vs baseline: 2.0200x; 1.1442x over previous
//
#include <hip/hip_runtime.h>

#define POOL 7
#define CCH 256
#define GCH 8             // channels per block (= waves per block)
#define HH 100
#define WW 100
#define HW (HH * WW)
#define MAXTH 28          // worst-case row span (<=26)
#define NTAP 14           // POOL * NSAMP samples per axis
#define RECI 128          // ints per ROI record
#define NT 512            // threads per main block

static constexpr float SCALE = 0.125f;

__device__ int g_rec[1024 * RECI];   // fallback if d_ws too small

__device__ __forceinline__ void tap_calc(float s0, float step, int k, int L,
                                         int& lo, int& hi, float& w1, float& w2)
{
    const int   p  = k >> 1, si = k & 1;
    const float g  = (float)p + ((float)si + 0.5f) * 0.5f;
    const float c  = s0 + g * step;
    const float Lf = (float)L;
    const bool  valid = (c > -1.0f) && (c < Lf);
    float cl = fminf(fmaxf(c, 0.0f), Lf - 1.0f);
    lo = (int)floorf(cl);
    if (lo > L - 1) lo = L - 1;
    hi = lo + 1;
    if (hi > L - 1) hi = L - 1;
    const float fr = cl - (float)lo;
    w1 = valid ? 1.0f - fr : 0.0f;
    w2 = valid ? fr : 0.0f;
}

// Per ROI: {n, xmin_al, ymin, TH, nb4, magic} + 28 taps (tile-relative).
// Taps are monotonic in k (bin_w, bin_h > 0), so bounds come from taps 0/13.
__global__ __launch_bounds__(64) void roi_pre(const float* __restrict__ rois,
                                              int* __restrict__ rec, int R)
{
    const int r = blockIdx.x;
    if (r >= R) return;
    int* rr = (rec ? rec : g_rec) + r * RECI;
    const int t = threadIdx.x;

    const float sx0 = rois[r * 5 + 1] * SCALE - 0.5f;
    const float sy0 = rois[r * 5 + 2] * SCALE - 0.5f;
    const float bw  = (rois[r * 5 + 3] * SCALE - 0.5f - sx0) * (1.0f / POOL);
    const float bh  = (rois[r * 5 + 4] * SCALE - 0.5f - sy0) * (1.0f / POOL);

    if (t < 2 * NTAP) {
        const int   axis = (t >= NTAP) ? 1 : 0;
        const int   k    = axis ? t - NTAP : t;
        const float s0   = axis ? sy0 : sx0;
        const float st   = axis ? bh : bw;
        const int   L    = axis ? HH : WW;
        int lo, hi, lo0, u0; float w1, w2, ua, ub;
        tap_calc(s0, st, k, L, lo, hi, w1, w2);
        tap_calc(s0, st, 0, L, lo0, u0, ua, ub);
        const int base = axis ? lo0 : (lo0 & ~3);
        int* tp = rr + 8 + (axis ? 4 * NTAP : 0) + k * 4;
        tp[0] = max(lo - base, 0);
        tp[1] = max(hi - base, 0);
        tp[2] = __float_as_int(w1);
        tp[3] = __float_as_int(w2);
    } else if (t == 2 * NTAP) {
        int xl0, xh0, xl13, xh13, yl0, yh0, yl13, yh13; float a, b;
        tap_calc(sx0, bw, 0,        WW, xl0,  xh0,  a, b);
        tap_calc(sx0, bw, NTAP - 1, WW, xl13, xh13, a, b);
        tap_calc(sy0, bh, 0,        HH, yl0,  yh0,  a, b);
        tap_calc(sy0, bh, NTAP - 1, HH, yl13, yh13, a, b);
        const int xmin_al = xl0 & ~3;
        int TH  = yh13 - yl0 + 1; if (TH > MAXTH) TH = MAXTH;
        int nb4 = (xh13 - xmin_al) / 4 + 1;           // 16B blocks per row
        if (nb4 > 8) nb4 = 8;
        rr[0] = (int)rois[r * 5 + 0];
        rr[1] = xmin_al;
        rr[2] = yl0;
        rr[3] = TH;
        rr[4] = nb4;
        rr[5] = (65536 + nb4 - 1) / nb4;              // magic: idx/nb4 exact
    }
}

// One block per (roi, 8-channel group), 512 threads (wave = channel).
// Tile rows packed to TWp = 4*nb4 floats -> staged bytes track the true
// ROI span. Async fire-and-forget global->LDS, one barrier.
__global__ __launch_bounds__(NT, 8) void roi_main(
    const float* __restrict__ x, const int* __restrict__ rec_in,
    float* __restrict__ out)
{
    __shared__ float tile[GCH * MAXTH * 32];      // worst case 28672 B
    __shared__ int   s_tap[2 * NTAP * 4];         // 448 B

    const int bid = blockIdx.x;
    const int r   = bid >> 5;                     // CCH/GCH = 32 groups/ROI
    const int c0  = (bid & 31) * GCH;
    const int t   = threadIdx.x;

    const int* rr = (rec_in ? rec_in : g_rec) + r * RECI;
    const int n       = rr[0];
    const int xmin_al = rr[1];
    const int ymin    = rr[2];
    const int TH      = rr[3];
    const int nb4     = rr[4];
    const int magic   = rr[5];

    if (t < 2 * NTAP * 4) s_tap[t] = rr[8 + t];

    const int chstride = TH * (nb4 << 2);         // floats per channel (packed)
    const int tot      = TH * nb4;                // 16B blocks per channel

    // ---- async staging: wave = channel, lanes enumerate packed blocks ----
    {
        const int ch   = t >> 6;                  // 0..7
        const int lane = t & 63;
        const float* xb = x + ((size_t)(n * CCH + c0 + ch)) * HW
                            + (size_t)ymin * WW + xmin_al;
        float* lbase = tile + ch * chstride;
        for (int idx = lane; idx < tot; idx += 64) {
            const int row = (idx * magic) >> 16;
            const int b   = idx - row * nb4;
            __builtin_amdgcn_global_load_lds(
                (const __attribute__((address_space(1))) void*)(xb + row * WW + (b << 2)),
                (__attribute__((address_space(3))) void*)(lbase + (idx << 2)),
                16, 0, 0);
        }
    }
    __syncthreads();

    // ---- compute: thread = (channel = t>>6, bin = t&63) ----
    const int ch  = t >> 6;
    const int bin = t & 63;
    if (bin < POOL * POOL) {
        const int py = bin / POOL;
        const int px = bin - py * POOL;
        const int TWp = nb4 << 2;
        const float* tc = tile + ch * chstride;
        float acc = 0.0f;
        #pragma unroll
        for (int sy = 0; sy < 2; ++sy) {
            const int* yt = s_tap + 4 * NTAP + (py * 2 + sy) * 4;
            const int   rowl = yt[0] * TWp;
            const int   rowh = yt[1] * TWp;
            const float wy1 = __int_as_float(yt[2]);
            const float wy2 = __int_as_float(yt[3]);
            #pragma unroll
            for (int sx = 0; sx < 2; ++sx) {
                const int* xt = s_tap + (px * 2 + sx) * 4;
                const int   xl  = xt[0], xh = xt[1];
                const float wx1 = __int_as_float(xt[2]);
                const float wx2 = __int_as_float(xt[3]);
                acc += wy1 * (wx1 * tc[rowl + xl] + wx2 * tc[rowl + xh])
                     + wy2 * (wx1 * tc[rowh + xl] + wx2 * tc[rowh + xh]);
            }
        }
        out[(size_t)(r * CCH + c0 + ch) * (POOL * POOL) + bin] = acc * 0.25f;
    }
}

extern "C" void kernel_launch(void* const* d_in, const int* in_sizes, int n_in,
                              void* d_out, int out_size, void* d_ws, size_t ws_size,
                              hipStream_t stream) {
    const float* x    = (const float*)d_in[0];
    const float* rois = (const float*)d_in[1];
    float*       out  = (float*)d_out;

    const int R = in_sizes[1] / 5;
    int* rec = (ws_size >= (size_t)R * RECI * sizeof(int)) ? (int*)d_ws : nullptr;

    roi_pre<<<R, 64, 0, stream>>>(rois, rec, R);
    roi_main<<<R * (CCH / GCH), NT, 0, stream>>>(x, rec, out);
}

// Round 6
// 41.791 us; speedup vs baseline: 2.0756x; 1.0275x over previous
//
#include <hip/hip_runtime.h>

#define POOL 7
#define CCH 256
#define GCH 4             // channels per block (= waves per block)
#define HH 100
#define WW 100
#define HW (HH * WW)
#define MAXTH 28          // worst-case row span (<=26)
#define NTAP 14           // POOL * NSAMP samples per axis
#define RECI 128          // ints per ROI record
#define NT 256            // threads per main block

static constexpr float SCALE = 0.125f;

__device__ __attribute__((aligned(16))) int g_rec[1024 * RECI];  // ws fallback

__device__ __forceinline__ void tap_calc(float s0, float step, int k, int L,
                                         int& lo, int& hi, float& w1, float& w2)
{
    const int   p  = k >> 1, si = k & 1;
    const float g  = (float)p + ((float)si + 0.5f) * 0.5f;
    const float c  = s0 + g * step;
    const float Lf = (float)L;
    const bool  valid = (c > -1.0f) && (c < Lf);
    float cl = fminf(fmaxf(c, 0.0f), Lf - 1.0f);
    lo = (int)floorf(cl);
    if (lo > L - 1) lo = L - 1;
    hi = lo + 1;
    if (hi > L - 1) hi = L - 1;
    const float fr = cl - (float)lo;
    w1 = valid ? 1.0f - fr : 0.0f;
    w2 = valid ? fr : 0.0f;
}

// Per ROI: {n, xmin_al, ymin, TH, nb4, magic} + 28 taps (tile-relative).
// Taps are monotonic in k (bin_w, bin_h > 0), so bounds come from taps 0/13.
__global__ __launch_bounds__(64) void roi_pre(const float* __restrict__ rois,
                                              int* __restrict__ rec, int R)
{
    const int r = blockIdx.x;
    if (r >= R) return;
    int* rr = (rec ? rec : g_rec) + r * RECI;
    const int t = threadIdx.x;

    const float sx0 = rois[r * 5 + 1] * SCALE - 0.5f;
    const float sy0 = rois[r * 5 + 2] * SCALE - 0.5f;
    const float bw  = (rois[r * 5 + 3] * SCALE - 0.5f - sx0) * (1.0f / POOL);
    const float bh  = (rois[r * 5 + 4] * SCALE - 0.5f - sy0) * (1.0f / POOL);

    if (t < 2 * NTAP) {
        const int   axis = (t >= NTAP) ? 1 : 0;
        const int   k    = axis ? t - NTAP : t;
        const float s0   = axis ? sy0 : sx0;
        const float st   = axis ? bh : bw;
        const int   L    = axis ? HH : WW;
        int lo, hi, lo0, u0; float w1, w2, ua, ub;
        tap_calc(s0, st, k, L, lo, hi, w1, w2);
        tap_calc(s0, st, 0, L, lo0, u0, ua, ub);
        const int base = axis ? lo0 : (lo0 & ~3);
        int* tp = rr + 8 + (axis ? 4 * NTAP : 0) + k * 4;
        tp[0] = max(lo - base, 0);
        tp[1] = max(hi - base, 0);
        tp[2] = __float_as_int(w1);
        tp[3] = __float_as_int(w2);
    } else if (t == 2 * NTAP) {
        int xl0, xh0, xl13, xh13, yl0, yh0, yl13, yh13; float a, b;
        tap_calc(sx0, bw, 0,        WW, xl0,  xh0,  a, b);
        tap_calc(sx0, bw, NTAP - 1, WW, xl13, xh13, a, b);
        tap_calc(sy0, bh, 0,        HH, yl0,  yh0,  a, b);
        tap_calc(sy0, bh, NTAP - 1, HH, yl13, yh13, a, b);
        const int xmin_al = xl0 & ~3;
        int TH  = yh13 - yl0 + 1; if (TH > MAXTH) TH = MAXTH;
        int nb4 = (xh13 - xmin_al) / 4 + 1;           // 16B blocks per row
        if (nb4 > 8) nb4 = 8;
        rr[0] = (int)rois[r * 5 + 0];
        rr[1] = xmin_al;
        rr[2] = yl0;
        rr[3] = TH;
        rr[4] = nb4;
        rr[5] = (65536 + nb4 - 1) / nb4;              // magic: idx/nb4 exact
    }
}

// One block per (roi, 4-channel group), 256 threads (wave = channel).
// 8 blocks/CU resident -> 8 independent load-latency chains per CU.
// Tap table AND tile staged by async global->LDS; single barrier.
__global__ __launch_bounds__(NT, 8) void roi_main(
    const float* __restrict__ x, const int* __restrict__ rec_in,
    float* __restrict__ out)
{
    __shared__ float tile[GCH * MAXTH * 32];      // 14336 B
    __shared__ int   s_tap[2 * NTAP * 4];         // 448 B

    const int bid = blockIdx.x;
    const int r   = bid >> 6;                     // CCH/GCH = 64 groups/ROI
    const int c0  = (bid & 63) * GCH;
    const int t   = threadIdx.x;

    const int* rr = (rec_in ? rec_in : g_rec) + r * RECI;
    const int n       = rr[0];
    const int xmin_al = rr[1];
    const int ymin    = rr[2];
    const int TH      = rr[3];
    const int nb4     = rr[4];
    const int magic   = rr[5];

    // ---- DMA tap table: wave 0, lanes 0..27, 16B each (lane-linear) ----
    if (t < 2 * NTAP) {
        __builtin_amdgcn_global_load_lds(
            (const __attribute__((address_space(1))) void*)(rr + 8 + t * 4),
            (__attribute__((address_space(3))) void*)(s_tap + t * 4),
            16, 0, 0);
    }

    const int chstride = TH * (nb4 << 2);         // floats per channel (packed)
    const int tot      = TH * nb4;                // 16B blocks per channel

    // ---- async tile staging: wave = channel, lanes enumerate blocks ----
    {
        const int ch   = t >> 6;                  // 0..3
        const int lane = t & 63;
        const float* xb = x + ((size_t)(n * CCH + c0 + ch)) * HW
                            + (size_t)ymin * WW + xmin_al;
        float* lbase = tile + ch * chstride;
        for (int idx = lane; idx < tot; idx += 64) {
            const int row = (idx * magic) >> 16;
            const int b   = idx - row * nb4;
            __builtin_amdgcn_global_load_lds(
                (const __attribute__((address_space(1))) void*)(xb + row * WW + (b << 2)),
                (__attribute__((address_space(3))) void*)(lbase + (idx << 2)),
                16, 0, 0);
        }
    }
    __syncthreads();

    // ---- compute: thread = (channel = t>>6, bin = t&63) ----
    const int ch  = t >> 6;
    const int bin = t & 63;
    if (bin < POOL * POOL) {
        const int py = bin / POOL;
        const int px = bin - py * POOL;
        const int TWp = nb4 << 2;
        const float* tc = tile + ch * chstride;
        float acc = 0.0f;
        #pragma unroll
        for (int sy = 0; sy < 2; ++sy) {
            const int* yt = s_tap + 4 * NTAP + (py * 2 + sy) * 4;
            const int   rowl = yt[0] * TWp;
            const int   rowh = yt[1] * TWp;
            const float wy1 = __int_as_float(yt[2]);
            const float wy2 = __int_as_float(yt[3]);
            #pragma unroll
            for (int sx = 0; sx < 2; ++sx) {
                const int* xt = s_tap + (px * 2 + sx) * 4;
                const int   xl  = xt[0], xh = xt[1];
                const float wx1 = __int_as_float(xt[2]);
                const float wx2 = __int_as_float(xt[3]);
                acc += wy1 * (wx1 * tc[rowl + xl] + wx2 * tc[rowl + xh])
                     + wy2 * (wx1 * tc[rowh + xl] + wx2 * tc[rowh + xh]);
            }
        }
        out[(size_t)(r * CCH + c0 + ch) * (POOL * POOL) + bin] = acc * 0.25f;
    }
}

extern "C" void kernel_launch(void* const* d_in, const int* in_sizes, int n_in,
                              void* d_out, int out_size, void* d_ws, size_t ws_size,
                              hipStream_t stream) {
    const float* x    = (const float*)d_in[0];
    const float* rois = (const float*)d_in[1];
    float*       out  = (float*)d_out;

    const int R = in_sizes[1] / 5;
    int* rec = (ws_size >= (size_t)R * RECI * sizeof(int)) ? (int*)d_ws : nullptr;

    roi_pre<<<R, 64, 0, stream>>>(rois, rec, R);
    roi_main<<<R * (CCH / GCH), NT, 0, stream>>>(x, rec, out);
}